// Round 8
// baseline (391.577 us; speedup 1.0000x reference)
//
#include <hip/hip_runtime.h>
#include <math.h>

// ---------------- problem constants ----------------
#define B_    4
#define CIN   16
#define COUT  32
#define DD    32
#define HH    128
#define WW    128
#define EPSF  1e-5f

typedef _Float16 half8 __attribute__((ext_vector_type(8)));
typedef float f32x16 __attribute__((ext_vector_type(16)));

// ws: weight fragments only — 27 taps * 2 planes * 64 lanes * 8 halfs
#define WFRAG_HALFS (27 * 2 * 64 * 8)                 // 27648 halfs = 55296 B
#define WS_NEEDED   ((size_t)WFRAG_HALFS * 2)

// =====================================================================
// pre-pass: weight fragments.
// wf[tap][plane][lane][j] = plane(w[co][ci][tap]), co=lane&31, ci=(lane>>5)*8+j
// plane0 = f16 hi (RNE), plane1 = f16 residual. w represented to ~2^-23.
// =====================================================================
__global__ void prep_w(const float* __restrict__ w, _Float16* __restrict__ wf) {
    int t = blockIdx.x * 256 + threadIdx.x;
    if (t >= 27 * 2 * 64) return;
    int lane = t & 63;
    int pp = t >> 6;
    int tap = pp >> 1, plane = pp & 1;
    int co = lane & 31, cih = lane >> 5;
    half8 o;
    #pragma unroll
    for (int j = 0; j < 8; ++j) {
        int ci = cih * 8 + j;
        float v = w[(co * CIN + ci) * 27 + tap];
        _Float16 hi = (_Float16)v;
        o[j] = plane ? (_Float16)(v - (float)hi) : hi;
    }
    *(half8*)(wf + (size_t)t * 8) = o;
}

// =====================================================================
// main conv: implicit GEMM, mfma_f32_32x32x16_f16, 2-term split:
//   x*w ≈ xh*wh + xh*wl   (xh = RNE f16 of x; dropped xl*w ~1.5e-4)
// Block tile: (TD=4, TH=4, TW=32), 512 threads = 8 waves: wave=(td, th2).
// Halo LDS: [cih(2)][sp(6*6*34)][8] halfs = 39168 B -> up to 4 blocks/CU.
// Per wave: 36 ds_read_b128, 108 MFMAs (kh-row sharing across 2 accs).
// =====================================================================
#define IDh 6
#define IHh 6
#define IWh 34
#define SPN (IDh * IHh * IWh)     // 1224
#define XS_HALFS (2 * SPN * 8)    // 19584 halfs = 39168 B

__launch_bounds__(512, 6)
__global__ void conv_mfma(const float* __restrict__ x,
                          const _Float16* __restrict__ wf,
                          const float* __restrict__ bias,
                          const float* __restrict__ mult,
                          float* __restrict__ out) {
    __shared__ _Float16 xs[XS_HALFS];

    const int tid  = threadIdx.x;
    const int lane = tid & 63;
    const int wid  = tid >> 6;

    const int wt = blockIdx.x & 3;     // W/32
    const int ht = blockIdx.x >> 2;    // H/4
    const int dt = blockIdx.y;         // D/4
    const int b  = blockIdx.z;
    const int w0 = wt * 32, h0 = ht * 4, d0 = dt * 4;

    // ---- stage fp32 halo -> f16 (RNE) LDS, hi plane only ----
    for (int i = tid; i < 2 * SPN; i += 512) {
        int cih = (i >= SPN) ? 1 : 0;
        int sp  = i - cih * SPN;
        int zd  = sp / (IHh * IWh);
        int r2  = sp - zd * (IHh * IWh);
        int yh  = r2 / IWh;
        int col = r2 - yh * IWh;
        int d = d0 + zd - 1, h = h0 + yh - 1, w = w0 + col - 1;
        half8 hi = {};
        if (((unsigned)d < DD) & ((unsigned)h < HH) & ((unsigned)w < WW)) {
            const float* gx = x + ((size_t)(b * CIN + cih * 8) * DD + d) * (HH * WW) + h * WW + w;
            #pragma unroll
            for (int j = 0; j < 8; ++j)
                hi[j] = (_Float16)gx[(size_t)j * DD * HH * WW];   // v_cvt_f16_f32 (RNE)
        }
        *(half8*)&xs[(size_t)(cih * SPN + sp) * 8] = hi;
    }
    __syncthreads();

    const int td  = wid >> 1;          // 0..3
    const int th2 = (wid & 1) * 2;     // 0 or 2
    const int cih = lane >> 5;
    const int wl  = lane & 31;

    f32x16 acc0 = {};
    f32x16 acc1 = {};

    const _Float16* aH  = xs + (size_t)(cih * SPN) * 8;
    const _Float16* wfl = wf + (size_t)lane * 8;

    half8 Ah0, Ah1, Ah2;                    // current input row, 3 kw windows
    half8 Xh0, Xh1, Xh2, Xl0, Xl1, Xl2;     // B rolling slot X
    half8 Yh0, Yh1, Yh2, Yl0, Yl1, Yl2;     // B rolling slot Y

#define LDB(BH0, BH1, BH2, BL0, BL1, BL2, KH) do {                         \
        const int t0 = (kd * 3 + (KH)) * 3;                                \
        BH0 = *(const half8*)(wfl + (size_t)((t0 + 0) * 2 + 0) * 512);     \
        BL0 = *(const half8*)(wfl + (size_t)((t0 + 0) * 2 + 1) * 512);     \
        BH1 = *(const half8*)(wfl + (size_t)((t0 + 1) * 2 + 0) * 512);     \
        BL1 = *(const half8*)(wfl + (size_t)((t0 + 1) * 2 + 1) * 512);     \
        BH2 = *(const half8*)(wfl + (size_t)((t0 + 2) * 2 + 0) * 512);     \
        BL2 = *(const half8*)(wfl + (size_t)((t0 + 2) * 2 + 1) * 512);     \
    } while (0)

#define LDA(R) do {                                                        \
        const int spb = ((td + kd) * IHh + th2 + (R)) * IWh + wl;          \
        Ah0 = *(const half8*)(aH + (size_t)(spb + 0) * 8);                 \
        Ah1 = *(const half8*)(aH + (size_t)(spb + 1) * 8);                 \
        Ah2 = *(const half8*)(aH + (size_t)(spb + 2) * 8);                 \
    } while (0)

#define DOT(ACC, BH0, BH1, BH2, BL0, BL1, BL2) do {                        \
        ACC = __builtin_amdgcn_mfma_f32_32x32x16_f16(Ah0, BH0, ACC, 0, 0, 0); \
        ACC = __builtin_amdgcn_mfma_f32_32x32x16_f16(Ah0, BL0, ACC, 0, 0, 0); \
        ACC = __builtin_amdgcn_mfma_f32_32x32x16_f16(Ah1, BH1, ACC, 0, 0, 0); \
        ACC = __builtin_amdgcn_mfma_f32_32x32x16_f16(Ah1, BL1, ACC, 0, 0, 0); \
        ACC = __builtin_amdgcn_mfma_f32_32x32x16_f16(Ah2, BH2, ACC, 0, 0, 0); \
        ACC = __builtin_amdgcn_mfma_f32_32x32x16_f16(Ah2, BL2, ACC, 0, 0, 0); \
    } while (0)

    #pragma unroll
    for (int kd = 0; kd < 3; ++kd) {
        // r=0: row th2+0 -> acc0 kh=0
        LDB(Xh0, Xh1, Xh2, Xl0, Xl1, Xl2, 0);
        LDA(0);
        DOT(acc0, Xh0, Xh1, Xh2, Xl0, Xl1, Xl2);
        // r=1: row th2+1 -> acc0 kh=1, acc1 kh=0
        LDB(Yh0, Yh1, Yh2, Yl0, Yl1, Yl2, 1);
        LDA(1);
        DOT(acc0, Yh0, Yh1, Yh2, Yl0, Yl1, Yl2);
        DOT(acc1, Xh0, Xh1, Xh2, Xl0, Xl1, Xl2);
        // r=2: row th2+2 -> acc0 kh=2, acc1 kh=1   (slot X now holds kh=2)
        LDB(Xh0, Xh1, Xh2, Xl0, Xl1, Xl2, 2);
        LDA(2);
        DOT(acc0, Xh0, Xh1, Xh2, Xl0, Xl1, Xl2);
        DOT(acc1, Yh0, Yh1, Yh2, Yl0, Yl1, Yl2);
        // r=3: row th2+3 -> acc1 kh=2
        LDA(3);
        DOT(acc1, Xh0, Xh1, Xh2, Xl0, Xl1, Xl2);
    }
#undef LDB
#undef LDA
#undef DOT

    // ---- epilogue: two passes (one per acc), 4224 B scratch per wave ----
    __syncthreads();   // input tile no longer needed; reuse xs as scratch

    float* sc = (float*)xs + (size_t)wid * (32 * 33);   // 8 waves * 4224 B = 33792 B
    const float mu = mult[wl];
    const float m1 = mu * (1.0f - 1.0f / (float)COUT);
    const float b1 = bias[wl] * m1;

    #pragma unroll
    for (int f = 0; f < 2; ++f) {
        const f32x16 acc = f ? acc1 : acc0;
        #pragma unroll
        for (int r = 0; r < 16; ++r) {
            int row = (r & 3) + 8 * (r >> 2) + 4 * cih;   // spatial w (verified C/D map)
            float t = fmaf(acc[r], m1, b1);
            float u = fabsf(t) + EPSF;
            float nr = t * rsqrtf(u);
            float cl = fminf(fmaxf(nr, -1.0f), 1.0f);     // -> v_med3
            sc[row * 33 + wl] = cl * mu;                  // stride 33: conflict-free
        }
        // within-wave RAW through LDS: compiler inserts lgkmcnt waits
        const float* rrow = sc + (size_t)(lane & 31) * 33;
        float v = -INFINITY;
        #pragma unroll
        for (int j = 0; j < 32; ++j) v = fmaxf(v, rrow[j]);
        if (lane < 32)
            out[(((size_t)b * DD + (d0 + td)) * HH + (h0 + th2 + f)) * WW + (w0 + lane)] = v;
    }
}

// =====================================================================
// fallback: fp32 vector kernel (zero ws required)
// =====================================================================
#define TDf 4
#define THf 8
#define TWf 8
#define IDf (TDf + 2)
#define IHf (THf + 2)
#define IWf (TWf + 2)
#define XSF_SIZE (CIN * IDf * IHf * IWf)

__launch_bounds__(256)
__global__ void conv_fused_fp32(const float* __restrict__ x,
                                const float* __restrict__ w,
                                const float* __restrict__ bias,
                                const float* __restrict__ mult,
                                float* __restrict__ out) {
    __shared__ float xsf[XSF_SIZE];
    const int tid = threadIdx.x;
    const int wt_ = blockIdx.x & 15;
    const int ht_ = blockIdx.x >> 4;
    const int dt_ = blockIdx.y;
    const int b   = blockIdx.z;
    const int w0 = wt_ * TWf, h0 = ht_ * THf, d0 = dt_ * TDf;

    const float* xb = x + (size_t)b * CIN * DD * HH * WW;
    for (int i = tid; i < XSF_SIZE; i += 256) {
        int ci = i / (IDf * IHf * IWf);
        int r  = i % (IDf * IHf * IWf);
        int zd = r / (IHf * IWf);
        int r2 = r % (IHf * IWf);
        int yh = r2 / IWf;
        int xw = r2 % IWf;
        int d = d0 + zd - 1, h = h0 + yh - 1, ww = w0 + xw - 1;
        float v = 0.0f;
        if ((unsigned)d < DD && (unsigned)h < HH && (unsigned)ww < WW)
            v = xb[((size_t)ci * DD + d) * (HH * WW) + h * WW + ww];
        xsf[i] = v;
    }
    __syncthreads();

    const int tw = tid & 7;
    const int th = (tid >> 3) & 7;
    const int td = tid >> 6;

    float acc[COUT];
    #pragma unroll
    for (int co = 0; co < COUT; ++co) acc[co] = 0.0f;

    #pragma unroll 1
    for (int ci = 0; ci < CIN; ++ci) {
        #pragma unroll
        for (int kd = 0; kd < 3; ++kd) {
            #pragma unroll
            for (int kh = 0; kh < 3; ++kh) {
                const float* xrow = &xsf[((ci * IDf + td + kd) * IHf + th + kh) * IWf + tw];
                const float x0 = xrow[0], x1 = xrow[1], x2 = xrow[2];
                const int idx = ci * 27 + kd * 9 + kh * 3;
                #pragma unroll
                for (int co = 0; co < COUT; ++co) {
                    const float* wr = w + co * (CIN * 27) + idx;
                    acc[co] = fmaf(x0, wr[0], acc[co]);
                    acc[co] = fmaf(x1, wr[1], acc[co]);
                    acc[co] = fmaf(x2, wr[2], acc[co]);
                }
            }
        }
    }

    const float cfac = 1.0f - 1.0f / (float)COUT;
    float best = -INFINITY;
    #pragma unroll
    for (int co = 0; co < COUT; ++co) {
        const float m = mult[co];
        const float y = (acc[co] + bias[co]) * m;
        const float t = y * cfac;
        const float nrm = t / sqrtf(fabsf(t) + EPSF);
        const float c = fminf(fmaxf(nrm, -1.0f), 1.0f);
        best = fmaxf(best, c * m);
    }
    out[((size_t)(b * DD + d0 + td) * HH + (h0 + th)) * WW + (w0 + tw)] = best;
}

// =====================================================================
extern "C" void kernel_launch(void* const* d_in, const int* in_sizes, int n_in,
                              void* d_out, int out_size, void* d_ws, size_t ws_size,
                              hipStream_t stream) {
    const float* x    = (const float*)d_in[0];
    const float* wgt  = (const float*)d_in[1];
    const float* bias = (const float*)d_in[2];
    const float* mult = (const float*)d_in[3];
    float* out = (float*)d_out;

    if (ws_size >= WS_NEEDED) {
        _Float16* wf = (_Float16*)d_ws;
        prep_w<<<14, 256, 0, stream>>>(wgt, wf);
        dim3 grid(4 * 32, 8, B_);   // (W/32 * H/4, D/4, B)
        conv_mfma<<<grid, 512, 0, stream>>>(x, wf, bias, mult, out);
    } else {
        dim3 grid(16 * 16, DD / TDf, B_);
        conv_fused_fp32<<<grid, 256, 0, stream>>>(x, wgt, bias, mult, out);
    }
}